// Round 10
// baseline (71.718 us; speedup 1.0000x reference)
//
#include <hip/hip_runtime.h>
#include <hip/hip_bf16.h>
#include <math.h>

#define BATCH 4096
#define TWO_B 8192
#define DIM 128
#define NB 16384
#define COS_EPS 1e-8f
#define LOSS_EPS 1e-6f
// 1/TEMP ; log2(e)/TEMP ; sqrt(log2(e)/TEMP) ; ln 2
#define INV_TEMP 14.285714285714286f
#define EXP2_SCALE 20.60992915555662f
#define SQRT_EXP2_SCALE 4.5398166f
#define LN2 0.6931471805599453f

#define N_NEAR 32768                 // nearby positive dots
#define NTILE 128                    // 64-row tiles over 8192 rows
#define NPAIRS 8256                  // #{(i,j): 0<=i<=j<128}
#define GRAM_BLOCKS (NPAIRS / 4)     // 2064 blocks, 4 independent waves each
#define RED_ROWS_PER_WAVE 4
#define RED_BLOCKS (TWO_B / (4 * RED_ROWS_PER_WAVE))  // 512

typedef __attribute__((ext_vector_type(8))) short bf16x8;
typedef __attribute__((ext_vector_type(4))) float f32x4;

__device__ __forceinline__ float fast_exp2(float x) {
#if __has_builtin(__builtin_amdgcn_exp2f)
  return __builtin_amdgcn_exp2f(x);
#else
  float r;
  asm("v_exp_f32 %0, %1" : "=v"(r) : "v"(x));
  return r;
#endif
}

__device__ __forceinline__ float2 bf2_to_f2(unsigned int w) {
  float2 r;
  r.x = __uint_as_float(w << 16);
  r.y = __uint_as_float(w & 0xffff0000u);
  return r;
}

// ---------------- K1: normalize za rows -> bf16 za_n (pre-scaled); inv_zn ----------------
__global__ __launch_bounds__(256) void k_normalize(
    const float* __restrict__ z1, const float* __restrict__ z2,
    const float* __restrict__ zn,
    __hip_bfloat16* __restrict__ za_n, float* __restrict__ inv_zn) {
  int wave = (blockIdx.x * blockDim.x + threadIdx.x) >> 6;
  int lane = threadIdx.x & 63;
  if (wave >= TWO_B + NB) return;
  const float* src;
  if (wave < BATCH) src = z1 + (size_t)wave * DIM;
  else if (wave < TWO_B) src = z2 + (size_t)(wave - BATCH) * DIM;
  else src = zn + (size_t)(wave - TWO_B) * DIM;
  float2 v = ((const float2*)src)[lane];
  float ss = v.x * v.x + v.y * v.y;
#pragma unroll
  for (int m = 1; m < 64; m <<= 1) ss += __shfl_xor(ss, m, 64);
  float inv = 1.0f / fmaxf(sqrtf(ss), COS_EPS);
  if (wave < TWO_B) {
    float s = inv * SQRT_EXP2_SCALE;   // fold exp2 scale into the data
    __hip_bfloat162 o;
    o.x = __float2bfloat16(v.x * s);
    o.y = __float2bfloat16(v.y * s);
    ((__hip_bfloat162*)(za_n + (size_t)wave * DIM))[lane] = o;
  } else {
    if (lane == 0) inv_zn[wave - TWO_B] = inv;
  }
}

// ---------------- K2: barrier-free symmetric Gram, one 64x64 tile per wave ----------------
// 8256 wave-tiles (i<=j<128); fragments loaded global->VGPR (za_n is L2-resident).
// Outputs (plain stores, disjoint): part_row[(i*128+j)*64 + lr], part_col[(j*128+i)*64 + lc],
// augpart[i] for tiles j==i+64; blocks 0..1023 also do 32 nearby-positive dots.
__global__ __launch_bounds__(256) void k_gram(
    const __hip_bfloat16* __restrict__ za_n, const float* __restrict__ zn,
    const float* __restrict__ inv_zn,
    float* __restrict__ part_row, float* __restrict__ part_col,
    float* __restrict__ pos_partial, float* __restrict__ augpart) {
  const int t = threadIdx.x;
  const int w = t >> 6, lane = t & 63;
  const int lhi = lane >> 4, llo = lane & 15;
  const int wid = blockIdx.x * 4 + w;          // wave-uniform tile id

  int rem = wid, i = 0;                        // map wid -> (i,j), i<=j<128
  while (rem >= NTILE - i) { rem -= NTILE - i; ++i; }
  const int j = i + rem;

  const char* za8 = (const char*)za_n;         // row stride 256 B
  // MFMA 16x16x32 A/B fragment: lane reads row (base + rt*16 + llo),
  // k-bytes [ks*64 + lhi*16, +16). Direct 16B global loads.
  const char* arow = za8 + (size_t)(i * 64 + llo) * 256 + lhi * 16;
  const char* brow = za8 + (size_t)(j * 64 + llo) * 256 + lhi * 16;

  f32x4 acc[4][4];
#pragma unroll
  for (int rt = 0; rt < 4; ++rt)
#pragma unroll
    for (int ct = 0; ct < 4; ++ct) acc[rt][ct] = (f32x4)0.0f;

#pragma unroll
  for (int ks = 0; ks < 4; ++ks) {
    bf16x8 af[4], bf[4];
#pragma unroll
    for (int rt = 0; rt < 4; ++rt)
      af[rt] = *(const bf16x8*)(arow + rt * 16 * 256 + ks * 64);
#pragma unroll
    for (int ct = 0; ct < 4; ++ct)
      bf[ct] = *(const bf16x8*)(brow + ct * 16 * 256 + ks * 64);
#pragma unroll
    for (int rt = 0; rt < 4; ++rt)
#pragma unroll
      for (int ct = 0; ct < 4; ++ct)
        acc[rt][ct] = __builtin_amdgcn_mfma_f32_16x16x32_bf16(
            af[rt], bf[ct], acc[rt][ct], 0, 0, 0);
  }

  // aug-positive extraction: tiles j == i + 64 hold cells with gcol == grow + BATCH
  if (j - i == 64) {
    float ap = 0.0f;
#pragma unroll
    for (int rt = 0; rt < 4; ++rt) {
      const int lrb = rt * 16 + lhi * 4;
#pragma unroll
      for (int ct = 0; ct < 4; ++ct) {
        const int lc = ct * 16 + llo;
#pragma unroll
        for (int g = 0; g < 4; ++g)
          if (lc == lrb + g) ap += acc[rt][ct][g];
      }
    }
#pragma unroll
    for (int m = 1; m < 64; m <<= 1) ap += __shfl_xor(ap, m, 64);
    if (lane == 0) augpart[i] = ap;            // one wave per i: plain store
  }

  // epilogue: exp2, strict-upper mask (only diagonal tiles mask anything), row+col sums
  float cp[4] = {0.0f, 0.0f, 0.0f, 0.0f};
#pragma unroll
  for (int rt = 0; rt < 4; ++rt) {
    const int growb = i * 64 + rt * 16 + lhi * 4;            // + g
    float rp[4] = {0.0f, 0.0f, 0.0f, 0.0f};
#pragma unroll
    for (int ct = 0; ct < 4; ++ct) {
      const int gcol = j * 64 + ct * 16 + llo;
#pragma unroll
      for (int g = 0; g < 4; ++g) {
        float e = fast_exp2(acc[rt][ct][g]);
        e = (gcol > growb + g) ? e : 0.0f;     // strict upper triangle only
        rp[g] += e;
        cp[ct] += e;
      }
    }
#pragma unroll
    for (int g = 0; g < 4; ++g) {
      float s = rp[g];
      s += __shfl_xor(s, 1, 64);
      s += __shfl_xor(s, 2, 64);
      s += __shfl_xor(s, 4, 64);
      s += __shfl_xor(s, 8, 64);
      if (llo == 0)
        part_row[((size_t)i * NTILE + j) * 64 + rt * 16 + lhi * 4 + g] = s;
    }
  }
#pragma unroll
  for (int ct = 0; ct < 4; ++ct) {
    float s = cp[ct];
    s += __shfl_xor(s, 16, 64);
    s += __shfl_xor(s, 32, 64);
    if (lhi == 0)
      part_col[((size_t)j * NTILE + i) * 64 + ct * 16 + llo] = s;
  }

  // ---- fused nearby positives: blocks 0..1023, 32 dots each (4 waves x 8) ----
  if (blockIdx.x < N_NEAR / 32) {
    const int sub = lane & 7;
    const int k = blockIdx.x * 32 + w * 8 + (lane >> 3);
    int zr, zc;
    if (k < BATCH)                { zr = BATCH + k; zc = k; }
    else if (k < BATCH + TWO_B)   { int q = k - BATCH;             zr = q; zc = q; }
    else if (k < BATCH + 2*TWO_B) { int q = k - BATCH - TWO_B;     zr = q; zc = q + BATCH; }
    else if (k < BATCH + 3*TWO_B) { int q = k - BATCH - 2*TWO_B;   zr = q; zc = q + 2*BATCH; }
    else                          { int q = k - BATCH - 3*TWO_B;   zr = q; zc = q + 3*BATCH; }
    const uint4* aro = (const uint4*)(za_n + (size_t)zr * DIM);    // 16B = 8 bf16
    const float4* bro = (const float4*)(zn + (size_t)zc * DIM);
    float d = 0.0f;
#pragma unroll
    for (int c = 0; c < 2; ++c) {
      uint4 aw = aro[sub * 2 + c];
      float4 b0 = bro[sub * 4 + c * 2];
      float4 b1 = bro[sub * 4 + c * 2 + 1];
      float2 q;
      q = bf2_to_f2(aw.x); d += q.x * b0.x + q.y * b0.y;
      q = bf2_to_f2(aw.y); d += q.x * b0.z + q.y * b0.w;
      q = bf2_to_f2(aw.z); d += q.x * b1.x + q.y * b1.y;
      q = bf2_to_f2(aw.w); d += q.x * b1.z + q.y * b1.w;
    }
    d += __shfl_xor(d, 1, 64);
    d += __shfl_xor(d, 2, 64);
    d += __shfl_xor(d, 4, 64);
    if (sub == 0) {
      float ds = d * inv_zn[zc] * SQRT_EXP2_SCALE;       // = sim * EXP2_SCALE
      pos_partial[k] = fminf(ds, EXP2_SCALE) * LN2;      // = min(sim,1) * INV_TEMP
    }
  }
}

// ---------------- K3: wave-per-row gather (129 slots -> 2 gated loads/lane) ----------------
__global__ __launch_bounds__(256) void k_reduce(
    const float* __restrict__ part_row, const float* __restrict__ part_col,
    const float* __restrict__ pos_partial, float* __restrict__ blkpart) {
  const int w = threadIdx.x >> 6, lane = threadIdx.x & 63;
  float s = 0.0f;
#pragma unroll
  for (int q = 0; q < RED_ROWS_PER_WAVE; ++q) {
    const int r = (blockIdx.x * 4 + w) * RED_ROWS_PER_WAVE + q;  // 0..8191
    const int I = r >> 6, rr = r & 63;
    const size_t base = (size_t)I * NTILE * 64 + rr;
    float v = 0.0f;
    // slot u = lane: row-part if u>=I, col-part if u<=I
    if (lane >= I) v += part_row[base + (size_t)lane * 64];
    if (lane <= I) v += part_col[base + (size_t)lane * 64];
    // slot u = lane + 64
    const int u2 = lane + 64;
    if (u2 >= I) v += part_row[base + (size_t)u2 * 64];
    if (u2 <= I) v += part_col[base + (size_t)u2 * 64];
#pragma unroll
    for (int m = 1; m < 64; m <<= 1) v += __shfl_xor(v, m, 64);
    if (lane == 0) {
      float tl = 8.0f * logf(v + LOSS_EPS);
      tl -= pos_partial[r];
      tl -= pos_partial[r + TWO_B];
      tl -= pos_partial[r + 2 * TWO_B];
      tl -= pos_partial[r + 3 * TWO_B];
      s += tl;
    }
  }
  __shared__ float red[4];
  if (lane == 0) red[w] = s;
  __syncthreads();
  if (threadIdx.x == 0) blkpart[blockIdx.x] = red[0] + red[1] + red[2] + red[3];
}

// ---------------- K4: final scalar ----------------
__global__ __launch_bounds__(256) void k_final(
    const float* __restrict__ blkpart, const float* __restrict__ augpart,
    float* __restrict__ out) {
  __shared__ float red[256];
  float s = blkpart[threadIdx.x] + blkpart[threadIdx.x + 256];
  if (threadIdx.x < 64) s -= 8.0f * LN2 * augpart[threadIdx.x];
  red[threadIdx.x] = s;
  __syncthreads();
  for (int st = 128; st > 0; st >>= 1) {
    if (threadIdx.x < st) red[threadIdx.x] += red[threadIdx.x + st];
    __syncthreads();
  }
  if (threadIdx.x == 0) out[0] = red[0] * (1.0f / 65536.0f);
}

extern "C" void kernel_launch(void* const* d_in, const int* in_sizes, int n_in,
                              void* d_out, int out_size, void* d_ws, size_t ws_size,
                              hipStream_t stream) {
  const float* z1 = (const float*)d_in[0];
  const float* z2 = (const float*)d_in[1];
  const float* zn = (const float*)d_in[2];
  float* out = (float*)d_out;

  char* ws = (char*)d_ws;
  __hip_bfloat16* za_n = (__hip_bfloat16*)ws;                      // 2 MB
  float* inv_zn      = (float*)(ws + 2097152);                     // 64 KB
  float* pos_partial = (float*)(ws + 2097152 + 65536);             // 128 KB
  float* part_row    = (float*)(ws + 2097152 + 65536 + 131072);             // 4 MB
  float* part_col    = (float*)(ws + 2097152 + 65536 + 131072 + 4194304);   // 4 MB
  float* augpart     = (float*)(ws + 2097152 + 65536 + 131072 + 8388608);   // 256 B
  float* blkpart     = (float*)(ws + 2097152 + 65536 + 131072 + 8388608 + 4096); // 2 KB

  // K1: normalize (6144 blocks)
  k_normalize<<<(TWO_B + NB) / 4, 256, 0, stream>>>(z1, z2, zn, za_n, inv_zn);
  // K2: barrier-free gram partials + fused nearby positives
  k_gram<<<GRAM_BLOCKS, 256, 0, stream>>>(za_n, zn, inv_zn, part_row, part_col,
                                          pos_partial, augpart);
  // K3: gather/log/subtract -> 512 block partials
  k_reduce<<<RED_BLOCKS, 256, 0, stream>>>(part_row, part_col, pos_partial, blkpart);
  // K4: final scalar
  k_final<<<1, 256, 0, stream>>>(blkpart, augpart, out);
}

// Round 11
// 48.928 us; speedup vs baseline: 1.4658x; 1.4658x over previous
//
#include <hip/hip_runtime.h>
#include <hip/hip_bf16.h>
#include <math.h>

#define BATCH 4096
#define TWO_B 8192
#define DIM 128
#define NB 16384
#define COS_EPS 1e-8f
#define LOSS_EPS 1e-6f
// 1/TEMP ; log2(e)/TEMP ; sqrt(log2(e)/TEMP) ; ln 2
#define INV_TEMP 14.285714285714286f
#define EXP2_SCALE 20.60992915555662f
#define SQRT_EXP2_SCALE 4.5398166f
#define LN2 0.6931471805599453f

#define N_NEAR 32768                // nearby positive dots
#define GRAM_BLOCKS 2080            // #{(I,J): 0<=I<=J<64}
#define LDS_STRIDE 144              // 128 B row + 16 B pad: conflict-free, immediate-offset reads

typedef __attribute__((ext_vector_type(8))) short bf16x8;
typedef __attribute__((ext_vector_type(4))) float f32x4;

__device__ __forceinline__ float fast_exp2(float x) {
#if __has_builtin(__builtin_amdgcn_exp2f)
  return __builtin_amdgcn_exp2f(x);
#else
  float r;
  asm("v_exp_f32 %0, %1" : "=v"(r) : "v"(x));
  return r;
#endif
}

__device__ __forceinline__ float2 bf2_to_f2(unsigned int w) {
  float2 r;
  r.x = __uint_as_float(w << 16);
  r.y = __uint_as_float(w & 0xffff0000u);
  return r;
}

// ---------------- K1: normalize za rows -> bf16 za_n (pre-scaled); inv_zn; zero augacc ----------------
__global__ __launch_bounds__(256) void k_normalize(
    const float* __restrict__ z1, const float* __restrict__ z2,
    const float* __restrict__ zn,
    __hip_bfloat16* __restrict__ za_n, float* __restrict__ inv_zn,
    float* __restrict__ augacc) {
  if (blockIdx.x == 0 && threadIdx.x == 0) augacc[0] = 0.0f;
  int wave = (blockIdx.x * blockDim.x + threadIdx.x) >> 6;
  int lane = threadIdx.x & 63;
  if (wave >= TWO_B + NB) return;
  const float* src;
  if (wave < BATCH) src = z1 + (size_t)wave * DIM;
  else if (wave < TWO_B) src = z2 + (size_t)(wave - BATCH) * DIM;
  else src = zn + (size_t)(wave - TWO_B) * DIM;
  float2 v = ((const float2*)src)[lane];
  float ss = v.x * v.x + v.y * v.y;
#pragma unroll
  for (int m = 1; m < 64; m <<= 1) ss += __shfl_xor(ss, m, 64);
  float inv = 1.0f / fmaxf(sqrtf(ss), COS_EPS);
  if (wave < TWO_B) {
    float s = inv * SQRT_EXP2_SCALE;   // fold exp2 scale into the data
    __hip_bfloat162 o;
    o.x = __float2bfloat16(v.x * s);
    o.y = __float2bfloat16(v.y * s);
    ((__hip_bfloat162*)(za_n + (size_t)wave * DIM))[lane] = o;
  } else {
    if (lane == 0) inv_zn[wave - TWO_B] = inv;
  }
}

// ---------------- K2: symmetric Gram, 128x128 tiles (I<=J), padded LDS, fused positives ----------------
// grid: 2080 blocks; block 256 thr = 4 waves of 64x64; LDS 36.9 KB (K split in 2 halves).
// Padded rows (stride 144 B): conflict-free ds access, ds_read addresses are base+immediate.
__global__ __launch_bounds__(256) void k_gram(
    const __hip_bfloat16* __restrict__ za_n, const float* __restrict__ zn,
    const float* __restrict__ inv_zn,
    float* __restrict__ part_row, float* __restrict__ part_col,
    float* __restrict__ pos_partial, float* __restrict__ augacc) {
  __shared__ char lds[2 * 128 * LDS_STRIDE];   // A then B
  char* ldsA = lds;
  char* ldsB = lds + 128 * LDS_STRIDE;
  const int t = threadIdx.x;
  int rem = blockIdx.x, I = 0;
  while (rem >= 64 - I) { rem -= 64 - I; ++I; }
  const int J = I + rem;
  const int Ibase = I * 128, Jbase = J * 128;
  const char* za8 = (const char*)za_n;   // byte view; row stride 256 B

  const int w = t >> 6, lane = t & 63;
  const int wr = w & 1, wc = w >> 1;     // 2x2 waves of 64x64
  const int lhi = lane >> 4, llo = lane & 15;

  // precomputed per-lane LDS bases (fragment reads use base + compile-time offsets)
  const int rdA0 = (wr * 64 + llo) * LDS_STRIDE + lhi * 16;
  const int rdB0 = (wc * 64 + llo) * LDS_STRIDE + lhi * 16;
  // staging: thread t writes rows (it*32 + t>>3), 16B chunk (t&7)
  const int st_row = t >> 3, st_kb = (t & 7) * 16;
  const int st_lds = st_row * LDS_STRIDE + st_kb;

  f32x4 acc[4][4];
#pragma unroll
  for (int rt = 0; rt < 4; ++rt)
#pragma unroll
    for (int ct = 0; ct < 4; ++ct) acc[rt][ct] = (f32x4)0.0f;

  for (int h = 0; h < 2; ++h) {
    if (h) __syncthreads();              // half-0 reads complete before overwrite
#pragma unroll
    for (int it = 0; it < 4; ++it) {
      uint4 d = *(const uint4*)(za8 + (size_t)(Ibase + it * 32 + st_row) * 256 + h * 128 + st_kb);
      *(uint4*)(ldsA + it * 32 * LDS_STRIDE + st_lds) = d;
    }
#pragma unroll
    for (int it = 0; it < 4; ++it) {
      uint4 d = *(const uint4*)(za8 + (size_t)(Jbase + it * 32 + st_row) * 256 + h * 128 + st_kb);
      *(uint4*)(ldsB + it * 32 * LDS_STRIDE + st_lds) = d;
    }
    __syncthreads();
#pragma unroll
    for (int ks = 0; ks < 2; ++ks) {
      bf16x8 af[4], bfr[4];
#pragma unroll
      for (int rt = 0; rt < 4; ++rt)
        af[rt] = *(const bf16x8*)(ldsA + rdA0 + rt * 16 * LDS_STRIDE + ks * 64);
#pragma unroll
      for (int ct = 0; ct < 4; ++ct)
        bfr[ct] = *(const bf16x8*)(ldsB + rdB0 + ct * 16 * LDS_STRIDE + ks * 64);
#pragma unroll
      for (int rt = 0; rt < 4; ++rt)
#pragma unroll
        for (int ct = 0; ct < 4; ++ct)
          acc[rt][ct] = __builtin_amdgcn_mfma_f32_16x16x32_bf16(
              af[rt], bfr[ct], acc[rt][ct], 0, 0, 0);
    }
  }

  // aug-positive extraction: cells with col == row + BATCH live in tiles J-I == 32
  if (J - I == 32) {
    float ap = 0.0f;
#pragma unroll
    for (int rt = 0; rt < 4; ++rt) {
      const int lrb = wr * 64 + rt * 16 + lhi * 4;
#pragma unroll
      for (int ct = 0; ct < 4; ++ct) {
        const int lc = wc * 64 + ct * 16 + llo;
#pragma unroll
        for (int g = 0; g < 4; ++g)
          if (lc == lrb + g) ap += acc[rt][ct][g];
      }
    }
#pragma unroll
    for (int m = 1; m < 64; m <<= 1) ap += __shfl_xor(ap, m, 64);
    if (lane == 0) atomicAdd(augacc, ap);
  }

  // epilogue: exp2 (+ diag mask only on I==J blocks); per-block row/col partials in LDS
  __syncthreads();                        // all MFMA LDS reads done; safe to alias lds
  float* lds_row = (float*)lds;           // [2][128] indexed [wc][localrow]
  float* lds_col = (float*)(lds + 1024);  // [2][128] indexed [wr][localcol]

  float cp[4] = {0.0f, 0.0f, 0.0f, 0.0f};
#pragma unroll
  for (int rt = 0; rt < 4; ++rt) {
    const int lrowb = wr * 64 + rt * 16 + lhi * 4;           // + g (local row)
    float rp[4] = {0.0f, 0.0f, 0.0f, 0.0f};
    if (I == J) {                          // wave-uniform branch
#pragma unroll
      for (int ct = 0; ct < 4; ++ct) {
        const int lcol = wc * 64 + ct * 16 + llo;
#pragma unroll
        for (int g = 0; g < 4; ++g) {
          float e = fast_exp2(acc[rt][ct][g]);
          e = (lcol > lrowb + g) ? e : 0.0f;   // strict upper triangle
          rp[g] += e;
          cp[ct] += e;
        }
      }
    } else {
#pragma unroll
      for (int ct = 0; ct < 4; ++ct)
#pragma unroll
        for (int g = 0; g < 4; ++g) {
          float e = fast_exp2(acc[rt][ct][g]);
          rp[g] += e;
          cp[ct] += e;
        }
    }
#pragma unroll
    for (int g = 0; g < 4; ++g) {
      float s = rp[g];
      s += __shfl_xor(s, 1, 64);
      s += __shfl_xor(s, 2, 64);
      s += __shfl_xor(s, 4, 64);
      s += __shfl_xor(s, 8, 64);
      if (llo == 0) lds_row[wc * 128 + lrowb + g] = s;
    }
  }
#pragma unroll
  for (int ct = 0; ct < 4; ++ct) {
    float s = cp[ct];
    s += __shfl_xor(s, 16, 64);
    s += __shfl_xor(s, 32, 64);
    if (lhi == 0) lds_col[wr * 128 + wc * 64 + ct * 16 + llo] = s;
  }
  __syncthreads();
  if (t < 128)
    part_row[(size_t)(I * 64 + J) * 128 + t] = lds_row[t] + lds_row[128 + t];
  else
    part_col[(size_t)(J * 64 + I) * 128 + (t - 128)] =
        lds_col[t - 128] + lds_col[t];

  // ---- fused nearby positives: blocks 0..1023, 32 dots each (4 waves x 8) ----
  if (blockIdx.x < N_NEAR / 32) {
    const int sub = lane & 7;
    const int k = blockIdx.x * 32 + w * 8 + (lane >> 3);
    int zr, zc;
    if (k < BATCH)                { zr = BATCH + k; zc = k; }
    else if (k < BATCH + TWO_B)   { int q = k - BATCH;             zr = q; zc = q; }
    else if (k < BATCH + 2*TWO_B) { int q = k - BATCH - TWO_B;     zr = q; zc = q + BATCH; }
    else if (k < BATCH + 3*TWO_B) { int q = k - BATCH - 2*TWO_B;   zr = q; zc = q + 2*BATCH; }
    else                          { int q = k - BATCH - 3*TWO_B;   zr = q; zc = q + 3*BATCH; }
    const uint4* aro = (const uint4*)(za_n + (size_t)zr * DIM);    // 16B = 8 bf16
    const float4* bro = (const float4*)(zn + (size_t)zc * DIM);
    float d = 0.0f;
#pragma unroll
    for (int c = 0; c < 2; ++c) {
      uint4 aw = aro[sub * 2 + c];
      float4 b0 = bro[sub * 4 + c * 2];
      float4 b1 = bro[sub * 4 + c * 2 + 1];
      float2 q;
      q = bf2_to_f2(aw.x); d += q.x * b0.x + q.y * b0.y;
      q = bf2_to_f2(aw.y); d += q.x * b0.z + q.y * b0.w;
      q = bf2_to_f2(aw.z); d += q.x * b1.x + q.y * b1.y;
      q = bf2_to_f2(aw.w); d += q.x * b1.z + q.y * b1.w;
    }
    d += __shfl_xor(d, 1, 64);
    d += __shfl_xor(d, 2, 64);
    d += __shfl_xor(d, 4, 64);
    if (sub == 0) {
      float ds = d * inv_zn[zc] * SQRT_EXP2_SCALE;       // = sim * EXP2_SCALE
      pos_partial[k] = fminf(ds, EXP2_SCALE) * LN2;      // = min(sim,1) * INV_TEMP
    }
  }
}

// ---------------- K3: wave-per-row-octet gather; lane l holds partial slot l ----------------
__global__ __launch_bounds__(256) void k_reduce(
    const float* __restrict__ part_row, const float* __restrict__ part_col,
    const float* __restrict__ pos_partial, float* __restrict__ blkpart) {
  const int w = threadIdx.x >> 6, lane = threadIdx.x & 63;
  float s = 0.0f;
#pragma unroll
  for (int i = 0; i < 8; ++i) {
    const int r = blockIdx.x * 32 + w * 8 + i;
    const int I = r >> 7, rr = r & 127;
    const size_t base = (size_t)(I * 64 + lane) * 128 + rr;
    float v = 0.0f;
    if (lane >= I) v += part_row[base];
    if (lane <= I) v += part_col[base];
#pragma unroll
    for (int m = 1; m < 64; m <<= 1) v += __shfl_xor(v, m, 64);
    if (lane == 0) {
      float tl = 8.0f * logf(v + LOSS_EPS);
      tl -= pos_partial[r];
      tl -= pos_partial[r + TWO_B];
      tl -= pos_partial[r + 2 * TWO_B];
      tl -= pos_partial[r + 3 * TWO_B];
      s += tl;
    }
  }
  __shared__ float red[4];
  if (lane == 0) red[w] = s;
  __syncthreads();
  if (threadIdx.x == 0) blkpart[blockIdx.x] = red[0] + red[1] + red[2] + red[3];
}

// ---------------- K4: final scalar ----------------
__global__ __launch_bounds__(256) void k_final(
    const float* __restrict__ blkpart, const float* __restrict__ augacc,
    float* __restrict__ out) {
  __shared__ float red[256];
  red[threadIdx.x] = blkpart[threadIdx.x];
  __syncthreads();
  for (int st = 128; st > 0; st >>= 1) {
    if (threadIdx.x < st) red[threadIdx.x] += red[threadIdx.x + st];
    __syncthreads();
  }
  if (threadIdx.x == 0)
    out[0] = (red[0] - 8.0f * LN2 * augacc[0]) * (1.0f / 65536.0f);
}

extern "C" void kernel_launch(void* const* d_in, const int* in_sizes, int n_in,
                              void* d_out, int out_size, void* d_ws, size_t ws_size,
                              hipStream_t stream) {
  const float* z1 = (const float*)d_in[0];
  const float* z2 = (const float*)d_in[1];
  const float* zn = (const float*)d_in[2];
  float* out = (float*)d_out;

  char* ws = (char*)d_ws;
  __hip_bfloat16* za_n = (__hip_bfloat16*)ws;                  // 2 MB
  float* inv_zn      = (float*)(ws + 2097152);                 // 64 KB
  float* pos_partial = (float*)(ws + 2097152 + 65536);         // 128 KB
  float* augacc      = (float*)(ws + 2097152 + 65536 + 131072);          // 4 KB slot
  float* part_row    = (float*)(ws + 2097152 + 65536 + 131072 + 4096);   // 2 MB
  float* part_col    = (float*)(ws + 2097152 + 65536 + 131072 + 4096 + 2097152); // 2 MB
  float* blkpart     = (float*)(ws + 2097152 + 65536 + 131072 + 4096 + 2097152 + 2097152); // 1 KB

  // K1: normalize + zero augacc
  k_normalize<<<(TWO_B + NB) / 4, 256, 0, stream>>>(z1, z2, zn, za_n, inv_zn, augacc);
  // K2: symmetric gram partials + fused nearby positives
  k_gram<<<GRAM_BLOCKS, 256, 0, stream>>>(za_n, zn, inv_zn, part_row, part_col,
                                          pos_partial, augacc);
  // K3: parallel gather/log/subtract -> 256 block partials
  k_reduce<<<256, 256, 0, stream>>>(part_row, part_col, pos_partial, blkpart);
  // K4: final scalar
  k_final<<<1, 256, 0, stream>>>(blkpart, augacc, out);
}